// Round 2
// 151.669 us; speedup vs baseline: 1.0062x; 1.0062x over previous
//
#include <hip/hip_runtime.h>
#include <math.h>

#define NB 64
#define HH 512
#define WW 512
#define KK 31
#define PP 15
#define TS 32                 // output rows per strip
#define NSTRIP (HH / TS)      // 16 strips per image
#define HR (TS + KK - 1)      // 62 H rows held in LDS
#define NPAIR (HR / 2)        // 31 row pairs in phase 1

typedef _Float16 f16;
typedef f16 f16x8 __attribute__((ext_vector_type(8)));
typedef f16 f16x4 __attribute__((ext_vector_type(4)));
typedef f16 f16x2 __attribute__((ext_vector_type(2)));

__device__ __forceinline__ f16x2 shfl_up2(f16x2 v, int delta) {
    int x = __shfl_up(__builtin_bit_cast(int, v), delta);
    return __builtin_bit_cast(f16x2, x);
}
__device__ __forceinline__ f16x2 shfl_dn2(f16x2 v, int delta) {
    int x = __shfl_down(__builtin_bit_cast(int, v), delta);
    return __builtin_bit_cast(f16x2, x);
}
__device__ __forceinline__ f16x2 sel2(bool c, f16x2 v) {
    f16x2 z = {(f16)0, (f16)0};
    return c ? v : z;
}

// ws layout: part[0..1023] = per-block inter, part[1024..2047] = per-block union
// block id = b * NSTRIP + strip

__global__ __launch_bounds__(512, 4) void dice_fused_kernel(
        const float* __restrict__ pred,
        const float* __restrict__ mask,
        float* __restrict__ part) {
    const int strip = blockIdx.x;
    const int b     = blockIdx.y;
    const int t     = threadIdx.x;
    const int wave  = t >> 6;
    const int lane  = t & 63;

    __shared__ f16 Hs[HR][WW];    // 62 x 512 fp16 = 63.5 KB : horizontal box sums
    __shared__ float red[16];     // total ~63.6 KB -> 2 blocks/CU

    const float* mb = mask + (size_t)b * HH * WW;
    const float* pb = pred + (size_t)b * HH * WW;
    const int y0 = strip * TS;

    // ============ Phase 1: H rows [y0-15, y0+46], 2 rows/iter, local-tap method ====
    // For lane l, output col x = 8l + j, window = cols [x-15, x+15] (zero padded):
    //   = suffix_{j+1..7}(lane l-2) + T(l-1) + T(l) + T(l+1) + prefix_{0..j-1}(lane l+2)
    // All terms are <=2-lane-distance shuffles of in-lane prefix sums: no serial
    // wave scan.  Two consecutive rows packed into f16x2 so each ds_bpermute
    // transports both rows (16 bpermutes / row-pair vs 23 / row before).
    const int xbase = lane * 8;
    const bool lm1 = (lane >= 1);   // T(l-1) valid
    const bool lm2 = (lane >= 2);   // suffix term valid
    const bool lp1 = (lane <= 62);  // T(l+1) valid
    const bool lp2 = (lane <= 61);  // prefix term valid

    #pragma unroll
    for (int k = 0; k < 4; ++k) {
        const int p = k * 8 + wave;          // pair index 0..30
        if (p >= NPAIR) continue;            // only wave 7, k=3 drops out
        const int ra = 2 * p;
        const int rb = ra + 1;
        const int gya = y0 + ra - PP;
        const int gyb = gya + 1;

        float va[8], vb[8];
        if (gya >= 0 && gya < HH) {
            const float* row = mb + (size_t)gya * WW + xbase;
            const float4 u = *(const float4*)(row);
            const float4 v = *(const float4*)(row + 4);
            va[0] = u.x; va[1] = u.y; va[2] = u.z; va[3] = u.w;
            va[4] = v.x; va[5] = v.y; va[6] = v.z; va[7] = v.w;
        } else {
            #pragma unroll
            for (int j = 0; j < 8; ++j) va[j] = 0.0f;
        }
        if (gyb >= 0 && gyb < HH) {
            const float* row = mb + (size_t)gyb * WW + xbase;
            const float4 u = *(const float4*)(row);
            const float4 v = *(const float4*)(row + 4);
            vb[0] = u.x; vb[1] = u.y; vb[2] = u.z; vb[3] = u.w;
            vb[4] = v.x; vb[5] = v.y; vb[6] = v.z; vb[7] = v.w;
        } else {
            #pragma unroll
            for (int j = 0; j < 8; ++j) vb[j] = 0.0f;
        }

        // in-lane inclusive prefixes (fp32)
        float sa[8], sb[8];
        sa[0] = va[0]; sb[0] = vb[0];
        #pragma unroll
        for (int j = 1; j < 8; ++j) { sa[j] = sa[j-1] + va[j]; sb[j] = sb[j-1] + vb[j]; }

        // pack both rows: ps[j] = (prefix_a[j], prefix_b[j]) as f16x2
        f16x2 ps[8];
        #pragma unroll
        for (int j = 0; j < 8; ++j) { ps[j][0] = (f16)sa[j]; ps[j][1] = (f16)sb[j]; }
        const f16x2 pT = ps[7];

        // independent shuffles (single latency level, no scan chain)
        f16x2 A[7];                              // suffix of lane l-2 after elem j
        #pragma unroll
        for (int j = 0; j < 7; ++j) A[j] = shfl_up2(pT - ps[j], 2);
        const f16x2 Bprev = shfl_up2(pT, 1);     // T(l-1)
        const f16x2 Cfull = shfl_dn2(pT, 1);     // T(l+1)
        f16x2 Cp[7];                             // prefix of lane l+2 up to elem j
        #pragma unroll
        for (int j = 0; j < 7; ++j) Cp[j] = shfl_dn2(ps[j], 2);

        f16x2 base = pT;
        base += sel2(lm1, Bprev);
        base += sel2(lp1, Cfull);

        f16x8 ha, hb;
        #pragma unroll
        for (int j = 0; j < 8; ++j) {
            f16x2 acc = base;
            if (j < 7) acc += sel2(lm2, A[j]);
            if (j > 0) acc += sel2(lp2, Cp[j-1]);
            ha[j] = acc[0];
            hb[j] = acc[1];
        }
        *(f16x8*)&Hs[ra][xbase] = ha;
        *(f16x8*)&Hs[rb][xbase] = hb;
    }
    __syncthreads();

    // ================= Phase 2: vertical running 31-sum + fused epilogue ===========
    // thread: 4 cols x 8 rows.  q = col group, g = row group.
    const int q  = t & 127;
    const int g  = t >> 7;               // 0..3
    const int c  = q * 4;
    const int r0 = g * 8;                // first output row (strip-relative)

    float4 B = make_float4(0.f, 0.f, 0.f, 0.f);
    #pragma unroll
    for (int j = 0; j < KK - 1; ++j) {   // H rows idx r0 .. r0+29
        const f16x4 h = *(const f16x4*)&Hs[r0 + j][c];
        B.x += (float)h[0]; B.y += (float)h[1]; B.z += (float)h[2]; B.w += (float)h[3];
    }

    float4 I4 = make_float4(0.f, 0.f, 0.f, 0.f);
    float4 U4 = make_float4(0.f, 0.f, 0.f, 0.f);
    const float inv2 = 1.0f / (float)(KK * KK);

    #pragma unroll
    for (int i = 0; i < 8; ++i) {
        const int y = y0 + r0 + i;
        const f16x4 he = *(const f16x4*)&Hs[r0 + i + (KK - 1)][c];
        const f16x4 hl = *(const f16x4*)&Hs[r0 + i][c];
        const float4 m4 = *(const float4*)(mb + (size_t)y * WW + c);   // L2-hot
        const float4 p4 = *(const float4*)(pb + (size_t)y * WW + c);

        B.x += (float)he[0]; B.y += (float)he[1]; B.z += (float)he[2]; B.w += (float)he[3];

        const float w0 = 1.0f + 5.0f * fabsf(B.x * inv2 - m4.x);
        const float w1 = 1.0f + 5.0f * fabsf(B.y * inv2 - m4.y);
        const float w2 = 1.0f + 5.0f * fabsf(B.z * inv2 - m4.z);
        const float w3 = 1.0f + 5.0f * fabsf(B.w * inv2 - m4.w);
        const float sg0 = 1.0f / (1.0f + __expf(-p4.x));
        const float sg1 = 1.0f / (1.0f + __expf(-p4.y));
        const float sg2 = 1.0f / (1.0f + __expf(-p4.z));
        const float sg3 = 1.0f / (1.0f + __expf(-p4.w));

        I4.x += sg0 * m4.x * w0;  U4.x += (sg0 + m4.x) * w0;
        I4.y += sg1 * m4.y * w1;  U4.y += (sg1 + m4.y) * w1;
        I4.z += sg2 * m4.z * w2;  U4.z += (sg2 + m4.z) * w2;
        I4.w += sg3 * m4.w * w3;  U4.w += (sg3 + m4.w) * w3;

        B.x -= (float)hl[0]; B.y -= (float)hl[1]; B.z -= (float)hl[2]; B.w -= (float)hl[3];
    }

    // ================= Block reduction -> per-block partials ======================
    float inter = I4.x + I4.y + I4.z + I4.w;
    float uni   = U4.x + U4.y + U4.z + U4.w;
    #pragma unroll
    for (int off = 32; off > 0; off >>= 1) {
        inter += __shfl_down(inter, off);
        uni   += __shfl_down(uni, off);
    }
    if (lane == 0) { red[wave] = inter; red[8 + wave] = uni; }
    __syncthreads();
    if (t == 0) {
        float ti = 0.f, tu = 0.f;
        #pragma unroll
        for (int w2 = 0; w2 < 8; ++w2) { ti += red[w2]; tu += red[8 + w2]; }
        const int bid = b * NSTRIP + strip;
        part[bid] = ti;
        part[NB * NSTRIP + bid] = tu;
    }
}

// ---------------- Final reduction ---------------
__global__ void dice_final_kernel(const float* __restrict__ part,
                                  float* __restrict__ out) {
    const int t = threadIdx.x;  // 64 threads, one per image
    float inter = 0.0f, uni = 0.0f;
    #pragma unroll
    for (int s = 0; s < NSTRIP; ++s) {
        inter += part[t * NSTRIP + s];
        uni   += part[NB * NSTRIP + t * NSTRIP + s];
    }
    float wd = 1.0f - (2.0f * inter + 0.5f) / (uni + 0.5f);
    #pragma unroll
    for (int off = 32; off > 0; off >>= 1) wd += __shfl_down(wd, off);
    if (t == 0) out[0] = wd * (1.0f / (float)NB);
}

extern "C" void kernel_launch(void* const* d_in, const int* in_sizes, int n_in,
                              void* d_out, int out_size, void* d_ws, size_t ws_size,
                              hipStream_t stream) {
    const float* pred = (const float*)d_in[0];
    const float* mask = (const float*)d_in[1];
    float* out  = (float*)d_out;
    float* part = (float*)d_ws;   // 2048 floats = 8 KB

    dim3 grid(NSTRIP, NB);        // 16 x 64 = 1024 blocks
    dice_fused_kernel<<<grid, 512, 0, stream>>>(pred, mask, part);
    dice_final_kernel<<<1, 64, 0, stream>>>(part, out);
}

// Round 3
// 149.795 us; speedup vs baseline: 1.0188x; 1.0125x over previous
//
#include <hip/hip_runtime.h>
#include <math.h>

#define NB 64
#define HH 512
#define WW 512
#define KK 31
#define PP 15
#define TS 32                 // output rows per strip
#define NSTRIP (HH / TS)      // 16 strips per image
#define HR (TS + KK - 1)      // 62 H rows held in LDS
#define NPAIR (HR / 2)        // 31 row pairs in phase 1

typedef _Float16 f16;
typedef f16 f16x8 __attribute__((ext_vector_type(8)));
typedef f16 f16x4 __attribute__((ext_vector_type(4)));
typedef f16 f16x2 __attribute__((ext_vector_type(2)));

__device__ __forceinline__ f16x2 shfl_up2(f16x2 v, int delta) {
    int x = __shfl_up(__builtin_bit_cast(int, v), delta);
    return __builtin_bit_cast(f16x2, x);
}
__device__ __forceinline__ f16x2 shfl_dn2(f16x2 v, int delta) {
    int x = __shfl_down(__builtin_bit_cast(int, v), delta);
    return __builtin_bit_cast(f16x2, x);
}
__device__ __forceinline__ f16x2 sel2(bool c, f16x2 v) {
    f16x2 z = {(f16)0, (f16)0};
    return c ? v : z;
}

// ws layout: part[0..1023] = per-block inter, part[1024..2047] = per-block union
// block id = b * NSTRIP + strip

__global__ __launch_bounds__(512, 4) void dice_fused_kernel(
        const float* __restrict__ pred,
        const float* __restrict__ mask,
        float* __restrict__ part) {
    const int strip = blockIdx.x;
    const int b     = blockIdx.y;
    const int t     = threadIdx.x;
    const int wave  = t >> 6;
    const int lane  = t & 63;

    __shared__ f16 Hs[HR][WW];    // 62 x 512 fp16 = 63.5 KB : horizontal box sums
    __shared__ float red[16];     // total ~63.6 KB -> 2 blocks/CU

    const float* mb = mask + (size_t)b * HH * WW;
    const float* pb = pred + (size_t)b * HH * WW;
    const int y0 = strip * TS;

    // ============ Phase 1: H rows [y0-15, y0+46], 2 rows/iter, local-tap method ====
    // MLP fix: ALL 16 dwordx4 loads (4 k-iterations x 4) issued before any compute
    // so ~16 KB/wave is in flight; compute rounds then consume in order.
    const int xbase = lane * 8;
    const bool lm1 = (lane >= 1);
    const bool lm2 = (lane >= 2);
    const bool lp1 = (lane <= 62);
    const bool lp2 = (lane <= 61);

    float va[4][8], vb[4][8];     // 64 VGPRs of staged rows
    #pragma unroll
    for (int k = 0; k < 4; ++k) {
        const int p = k * 8 + wave;          // pair index 0..31 (31 invalid)
        const int gya = y0 + 2 * p - PP;
        const int gyb = gya + 1;
        const bool pa = (p < NPAIR) && (gya >= 0) && (gya < HH);
        const bool qb = (p < NPAIR) && (gyb >= 0) && (gyb < HH);
        if (pa) {
            const float* row = mb + (size_t)gya * WW + xbase;
            const float4 u = *(const float4*)(row);
            const float4 v = *(const float4*)(row + 4);
            va[k][0] = u.x; va[k][1] = u.y; va[k][2] = u.z; va[k][3] = u.w;
            va[k][4] = v.x; va[k][5] = v.y; va[k][6] = v.z; va[k][7] = v.w;
        } else {
            #pragma unroll
            for (int j = 0; j < 8; ++j) va[k][j] = 0.0f;
        }
        if (qb) {
            const float* row = mb + (size_t)gyb * WW + xbase;
            const float4 u = *(const float4*)(row);
            const float4 v = *(const float4*)(row + 4);
            vb[k][0] = u.x; vb[k][1] = u.y; vb[k][2] = u.z; vb[k][3] = u.w;
            vb[k][4] = v.x; vb[k][5] = v.y; vb[k][6] = v.z; vb[k][7] = v.w;
        } else {
            #pragma unroll
            for (int j = 0; j < 8; ++j) vb[k][j] = 0.0f;
        }
    }

    #pragma unroll
    for (int k = 0; k < 4; ++k) {
        const int p = k * 8 + wave;
        if (p >= NPAIR) continue;            // only wave 7, k=3 drops out
        const int ra = 2 * p;
        const int rb = ra + 1;

        // in-lane inclusive prefixes (fp32)
        float sa[8], sb[8];
        sa[0] = va[k][0]; sb[0] = vb[k][0];
        #pragma unroll
        for (int j = 1; j < 8; ++j) { sa[j] = sa[j-1] + va[k][j]; sb[j] = sb[j-1] + vb[k][j]; }

        // pack both rows: ps[j] = (prefix_a[j], prefix_b[j]) as f16x2
        f16x2 ps[8];
        #pragma unroll
        for (int j = 0; j < 8; ++j) { ps[j][0] = (f16)sa[j]; ps[j][1] = (f16)sb[j]; }
        const f16x2 pT = ps[7];

        // independent shuffles (single latency level, no scan chain)
        f16x2 A[7];                              // suffix of lane l-2 after elem j
        #pragma unroll
        for (int j = 0; j < 7; ++j) A[j] = shfl_up2(pT - ps[j], 2);
        const f16x2 Bprev = shfl_up2(pT, 1);     // T(l-1)
        const f16x2 Cfull = shfl_dn2(pT, 1);     // T(l+1)
        f16x2 Cp[7];                             // prefix of lane l+2 up to elem j
        #pragma unroll
        for (int j = 0; j < 7; ++j) Cp[j] = shfl_dn2(ps[j], 2);

        f16x2 base = pT;
        base += sel2(lm1, Bprev);
        base += sel2(lp1, Cfull);

        f16x8 ha, hb;
        #pragma unroll
        for (int j = 0; j < 8; ++j) {
            f16x2 acc = base;
            if (j < 7) acc += sel2(lm2, A[j]);
            if (j > 0) acc += sel2(lp2, Cp[j-1]);
            ha[j] = acc[0];
            hb[j] = acc[1];
        }
        *(f16x8*)&Hs[ra][xbase] = ha;
        *(f16x8*)&Hs[rb][xbase] = hb;
    }
    __syncthreads();

    // ================= Phase 2: vertical running 31-sum + fused epilogue ===========
    // thread: 4 cols x 8 rows.  q = col group, g = row group.
    const int q  = t & 127;
    const int g  = t >> 7;               // 0..3
    const int c  = q * 4;
    const int r0 = g * 8;                // first output row (strip-relative)

    // MLP fix: all 16 global loads (8 rows x {mask,pred}) issued up front; the
    // 30-row LDS window init below hides their latency.
    float4 M[8], Pq[8];
    #pragma unroll
    for (int i = 0; i < 8; ++i) {
        const int y = y0 + r0 + i;
        M[i]  = *(const float4*)(mb + (size_t)y * WW + c);
        Pq[i] = *(const float4*)(pb + (size_t)y * WW + c);
    }

    float4 B = make_float4(0.f, 0.f, 0.f, 0.f);
    #pragma unroll
    for (int j = 0; j < KK - 1; ++j) {   // H rows idx r0 .. r0+29
        const f16x4 h = *(const f16x4*)&Hs[r0 + j][c];
        B.x += (float)h[0]; B.y += (float)h[1]; B.z += (float)h[2]; B.w += (float)h[3];
    }

    float4 I4 = make_float4(0.f, 0.f, 0.f, 0.f);
    float4 U4 = make_float4(0.f, 0.f, 0.f, 0.f);
    const float inv2 = 1.0f / (float)(KK * KK);

    #pragma unroll
    for (int i = 0; i < 8; ++i) {
        const f16x4 he = *(const f16x4*)&Hs[r0 + i + (KK - 1)][c];
        const f16x4 hl = *(const f16x4*)&Hs[r0 + i][c];
        const float4 m4 = M[i];
        const float4 p4 = Pq[i];

        B.x += (float)he[0]; B.y += (float)he[1]; B.z += (float)he[2]; B.w += (float)he[3];

        const float w0 = 1.0f + 5.0f * fabsf(B.x * inv2 - m4.x);
        const float w1 = 1.0f + 5.0f * fabsf(B.y * inv2 - m4.y);
        const float w2 = 1.0f + 5.0f * fabsf(B.z * inv2 - m4.z);
        const float w3 = 1.0f + 5.0f * fabsf(B.w * inv2 - m4.w);
        const float sg0 = 1.0f / (1.0f + __expf(-p4.x));
        const float sg1 = 1.0f / (1.0f + __expf(-p4.y));
        const float sg2 = 1.0f / (1.0f + __expf(-p4.z));
        const float sg3 = 1.0f / (1.0f + __expf(-p4.w));

        I4.x += sg0 * m4.x * w0;  U4.x += (sg0 + m4.x) * w0;
        I4.y += sg1 * m4.y * w1;  U4.y += (sg1 + m4.y) * w1;
        I4.z += sg2 * m4.z * w2;  U4.z += (sg2 + m4.z) * w2;
        I4.w += sg3 * m4.w * w3;  U4.w += (sg3 + m4.w) * w3;

        B.x -= (float)hl[0]; B.y -= (float)hl[1]; B.z -= (float)hl[2]; B.w -= (float)hl[3];
    }

    // ================= Block reduction -> per-block partials ======================
    float inter = I4.x + I4.y + I4.z + I4.w;
    float uni   = U4.x + U4.y + U4.z + U4.w;
    #pragma unroll
    for (int off = 32; off > 0; off >>= 1) {
        inter += __shfl_down(inter, off);
        uni   += __shfl_down(uni, off);
    }
    if (lane == 0) { red[wave] = inter; red[8 + wave] = uni; }
    __syncthreads();
    if (t == 0) {
        float ti = 0.f, tu = 0.f;
        #pragma unroll
        for (int w2 = 0; w2 < 8; ++w2) { ti += red[w2]; tu += red[8 + w2]; }
        const int bid = b * NSTRIP + strip;
        part[bid] = ti;
        part[NB * NSTRIP + bid] = tu;
    }
}

// ---------------- Final reduction ---------------
__global__ void dice_final_kernel(const float* __restrict__ part,
                                  float* __restrict__ out) {
    const int t = threadIdx.x;  // 64 threads, one per image
    float inter = 0.0f, uni = 0.0f;
    #pragma unroll
    for (int s = 0; s < NSTRIP; ++s) {
        inter += part[t * NSTRIP + s];
        uni   += part[NB * NSTRIP + t * NSTRIP + s];
    }
    float wd = 1.0f - (2.0f * inter + 0.5f) / (uni + 0.5f);
    #pragma unroll
    for (int off = 32; off > 0; off >>= 1) wd += __shfl_down(wd, off);
    if (t == 0) out[0] = wd * (1.0f / (float)NB);
}

extern "C" void kernel_launch(void* const* d_in, const int* in_sizes, int n_in,
                              void* d_out, int out_size, void* d_ws, size_t ws_size,
                              hipStream_t stream) {
    const float* pred = (const float*)d_in[0];
    const float* mask = (const float*)d_in[1];
    float* out  = (float*)d_out;
    float* part = (float*)d_ws;   // 2048 floats = 8 KB

    dim3 grid(NSTRIP, NB);        // 16 x 64 = 1024 blocks
    dice_fused_kernel<<<grid, 512, 0, stream>>>(pred, mask, part);
    dice_final_kernel<<<1, 64, 0, stream>>>(part, out);
}